// Round 3
// baseline (20.078 us; speedup 1.0000x reference)
//
#include <hip/hip_runtime.h>

// MahalanobisClassifier, fused single dispatch, 2 blocks/CU.
// out[b,c] = -( sum_d x^2*w - 2 sum_d x*(p*w) + s[c] ),  w = exp(ld)
// bf16 MFMA GEMM, K=512 concat processed as two K=256 halves through a
// half-size (64 KB) LDS so two blocks fit per CU (latency hiding).
// Half-0 prep does ALL global reads + VALU (exp, pw, x^2, s); half-1
// fragments (x raw, -2*p*w) are kept bf16-packed in registers, so half-1
// prep is just 16 ds_write_b128 per thread.
//
// Block 256 threads (4 waves 2x2, wave tile 32x32), grid (32,16):
//   blockIdx.x -> 64 rows, blockIdx.y -> 64 classes (C padded 1000->1024)
// LDS fragment order [tile16][ktile][lane][8 bf16] => lane-linear, conflict-free.

#define C_N 1000
#define D_N 256

typedef __attribute__((ext_vector_type(8))) short bf16x8;
typedef __attribute__((ext_vector_type(4))) float f32x4;

__device__ inline short f2bf(float f) {
  unsigned int u = __float_as_uint(f);
  unsigned int lsb = (u >> 16) & 1u;
  u += 0x7fffu + lsb;
  return (short)(u >> 16);
}

__device__ inline bf16x8 pack8(const float* v) {
  bf16x8 o;
#pragma unroll
  for (int j = 0; j < 8; ++j) o[j] = f2bf(v[j]);
  return o;
}

__global__ __launch_bounds__(256, 2) void mahal_fused(
    const float* __restrict__ x, const float* __restrict__ p,
    const float* __restrict__ ld, float* __restrict__ out) {
  __shared__ short lA[4][8][64][8];   // 32 KB: one K-half of A', frag order
  __shared__ short lB[4][8][64][8];   // 32 KB
  __shared__ float s_lds[64];

  const int tid = threadIdx.x;
  const int w   = tid >> 6;      // wave 0..3
  const int l   = tid & 63;
  const int r16 = l & 15;
  const int hi  = l >> 4;
  const int bx  = blockIdx.x;    // 0..31 : rows bx*64..+63
  const int by  = blockIdx.y;    // 0..15 : cols by*64..+63

  bf16x8 xa_sv[8];   // half-1 A frags: raw x
  bf16x8 pw_sv[8];   // half-1 B frags: -2*p*w

  // ---------------- half-0 prep (all loads + all VALU) ----------------
  {
    // B': wave owns class-tile w. half-0 value = w = exp(ld); also build pw, s.
    const int c = by * 64 + w * 16 + r16;
    const bool valid = (c < C_N);
    float sp = 0.f;
#pragma unroll
    for (int t = 0; t < 8; ++t) {
      const int d = t * 32 + hi * 8;
      float wv[8], pwv[8];
      if (valid) {
        const float* lp = ld + (size_t)c * D_N + d;
        const float* pp = p  + (size_t)c * D_N + d;
        float4 l0 = *reinterpret_cast<const float4*>(lp);
        float4 l1 = *reinterpret_cast<const float4*>(lp + 4);
        float4 p0 = *reinterpret_cast<const float4*>(pp);
        float4 p1 = *reinterpret_cast<const float4*>(pp + 4);
        float lv[8] = {l0.x,l0.y,l0.z,l0.w,l1.x,l1.y,l1.z,l1.w};
        float pv[8] = {p0.x,p0.y,p0.z,p0.w,p1.x,p1.y,p1.z,p1.w};
#pragma unroll
        for (int j = 0; j < 8; ++j) {
          float wj = __expf(lv[j]);
          wv[j]  = wj;
          pwv[j] = -2.f * pv[j] * wj;
          sp += pv[j] * pv[j] * wj;
        }
      } else {
#pragma unroll
        for (int j = 0; j < 8; ++j) { wv[j] = 0.f; pwv[j] = 0.f; }
      }
      *reinterpret_cast<bf16x8*>(&lB[w][t][l][0]) = pack8(wv);
      pw_sv[t] = pack8(pwv);
    }
    sp += __shfl_xor(sp, 16, 64);
    sp += __shfl_xor(sp, 32, 64);
    if (l < 16) s_lds[w * 16 + r16] = sp;

    // A': wave owns row-tile w. half-0 value = x^2; save raw-x frags.
    const int row = bx * 64 + w * 16 + r16;
#pragma unroll
    for (int t = 0; t < 8; ++t) {
      const int d = t * 32 + hi * 8;
      const float* xp = x + (size_t)row * D_N + d;
      float4 v0 = *reinterpret_cast<const float4*>(xp);
      float4 v1 = *reinterpret_cast<const float4*>(xp + 4);
      float v[8] = {v0.x,v0.y,v0.z,v0.w,v1.x,v1.y,v1.z,v1.w};
      float sq[8];
#pragma unroll
      for (int j = 0; j < 8; ++j) sq[j] = v[j] * v[j];
      *reinterpret_cast<bf16x8*>(&lA[w][t][l][0]) = pack8(sq);
      xa_sv[t] = pack8(v);
    }
  }
  __syncthreads();

  const int wm = w >> 1, wn = w & 1;
  f32x4 acc[2][2];
#pragma unroll
  for (int i = 0; i < 2; ++i)
#pragma unroll
    for (int jn = 0; jn < 2; ++jn) acc[i][jn] = {0.f, 0.f, 0.f, 0.f};

  // ---------------- compute half-0 ----------------
#pragma unroll
  for (int kt = 0; kt < 8; ++kt) {
    bf16x8 a0 = *reinterpret_cast<const bf16x8*>(&lA[wm * 2 + 0][kt][l][0]);
    bf16x8 a1 = *reinterpret_cast<const bf16x8*>(&lA[wm * 2 + 1][kt][l][0]);
    bf16x8 b0 = *reinterpret_cast<const bf16x8*>(&lB[wn * 2 + 0][kt][l][0]);
    bf16x8 b1 = *reinterpret_cast<const bf16x8*>(&lB[wn * 2 + 1][kt][l][0]);
    acc[0][0] = __builtin_amdgcn_mfma_f32_16x16x32_bf16(a0, b0, acc[0][0], 0, 0, 0);
    acc[0][1] = __builtin_amdgcn_mfma_f32_16x16x32_bf16(a0, b1, acc[0][1], 0, 0, 0);
    acc[1][0] = __builtin_amdgcn_mfma_f32_16x16x32_bf16(a1, b0, acc[1][0], 0, 0, 0);
    acc[1][1] = __builtin_amdgcn_mfma_f32_16x16x32_bf16(a1, b1, acc[1][1], 0, 0, 0);
  }
  __syncthreads();   // all waves done reading half-0 LDS

  // ---------------- half-1 prep: pure register -> LDS ----------------
#pragma unroll
  for (int t = 0; t < 8; ++t) {
    *reinterpret_cast<bf16x8*>(&lA[w][t][l][0]) = xa_sv[t];
    *reinterpret_cast<bf16x8*>(&lB[w][t][l][0]) = pw_sv[t];
  }
  __syncthreads();

  // ---------------- compute half-1 ----------------
#pragma unroll
  for (int kt = 0; kt < 8; ++kt) {
    bf16x8 a0 = *reinterpret_cast<const bf16x8*>(&lA[wm * 2 + 0][kt][l][0]);
    bf16x8 a1 = *reinterpret_cast<const bf16x8*>(&lA[wm * 2 + 1][kt][l][0]);
    bf16x8 b0 = *reinterpret_cast<const bf16x8*>(&lB[wn * 2 + 0][kt][l][0]);
    bf16x8 b1 = *reinterpret_cast<const bf16x8*>(&lB[wn * 2 + 1][kt][l][0]);
    acc[0][0] = __builtin_amdgcn_mfma_f32_16x16x32_bf16(a0, b0, acc[0][0], 0, 0, 0);
    acc[0][1] = __builtin_amdgcn_mfma_f32_16x16x32_bf16(a0, b1, acc[0][1], 0, 0, 0);
    acc[1][0] = __builtin_amdgcn_mfma_f32_16x16x32_bf16(a1, b0, acc[1][0], 0, 0, 0);
    acc[1][1] = __builtin_amdgcn_mfma_f32_16x16x32_bf16(a1, b1, acc[1][1], 0, 0, 0);
  }

  // ---------------- epilogue ----------------
  // C/D layout: col = lane&15, row = (lane>>4)*4 + reg  [verified rounds 1-2]
  const int colbase = by * 64 + wn * 32 + r16;
  const int rowbase = bx * 64 + wm * 32 + hi * 4;
#pragma unroll
  for (int jn = 0; jn < 2; ++jn) {
    const int col = colbase + jn * 16;
    if (col < C_N) {
      const float sc = s_lds[wn * 32 + jn * 16 + r16];
#pragma unroll
      for (int i = 0; i < 2; ++i) {
        const int row = rowbase + i * 16;
#pragma unroll
        for (int r = 0; r < 4; ++r)
          out[(size_t)(row + r) * C_N + col] = -(acc[i][jn][r] + sc);
      }
    }
  }
}

extern "C" void kernel_launch(void* const* d_in, const int* in_sizes, int n_in,
                              void* d_out, int out_size, void* d_ws, size_t ws_size,
                              hipStream_t stream) {
  const float* x  = (const float*)d_in[0];
  const float* p  = (const float*)d_in[1];
  const float* ld = (const float*)d_in[2];
  float* out = (float*)d_out;
  mahal_fused<<<dim3(32, 16), 256, 0, stream>>>(x, p, ld, out);
}

// Round 4
// 17.044 us; speedup vs baseline: 1.1780x; 1.1780x over previous
//
#include <hip/hip_runtime.h>
#include <hip/hip_bf16.h>

// MahalanobisClassifier, fused single dispatch.
// out[b,c] = -( sum_d x^2*w - 2 sum_d x*(p*w) + s[c] ),  w = exp(ld)
// bf16 MFMA GEMM, K=512 concat: A'=[x^2 | x], B'=[w | -2*p*w], s in epilogue.
//
// Block: 512 threads (8 waves, 4x2), tile 128 rows x 64 classes, grid (16,16).
// LDS 128 KB: lB = full-K B' (64 KB), lA = all 128 rows x one K-half (64 KB).
// Phase 0: A-half = x^2 (vs w);  Phase 1: A-half = raw x (vs -2pw), written
// from registers saved in phase-0 prep. acc accumulates across phases in-wave.
// All LDS chunks are [tile16][ktile][lane][8 bf16] -> lane-linear, 0 conflicts.

#define C_N 1000
#define D_N 256

typedef __attribute__((ext_vector_type(8))) short bf16x8;
typedef __attribute__((ext_vector_type(4))) float f32x4;

__device__ inline bf16x8 pack8(const float* v) {
  union { bf16x8 o; __hip_bfloat162 h[4]; } u;
#pragma unroll
  for (int j = 0; j < 4; ++j)
    u.h[j] = __float22bfloat162_rn(make_float2(v[2 * j], v[2 * j + 1]));
  return u.o;
}

__global__ __launch_bounds__(512, 2) void mahal_fused(
    const float* __restrict__ x, const float* __restrict__ p,
    const float* __restrict__ ld, float* __restrict__ out) {
  __shared__ short lA[8][8][64][8];    // 64 KB: 8 row-tiles x 8 ktiles (one K-half)
  __shared__ short lB[4][16][64][8];   // 64 KB: 4 class-tiles x 16 ktiles (full K)
  __shared__ float s_lds[2][64];

  const int tid = threadIdx.x;
  const int w   = tid >> 6;        // wave 0..7
  const int l   = tid & 63;
  const int r16 = l & 15;
  const int hi  = l >> 4;
  const int bx  = blockIdx.x;      // rows bx*128..+127
  const int by  = blockIdx.y;      // cols by*64..+63

  bf16x8 xa_sv[8];                 // raw-x frags for phase 1 (32 VGPRs)

  // ---------------- prep: B' full (waves split (ct, d-half)) ----------------
  {
    const int ct = w & 3;          // class-tile 0..3
    const int dh = w >> 2;         // d-half 0..1
    const int c  = by * 64 + ct * 16 + r16;
    const bool valid = (c < C_N);
    float sp = 0.f;
#pragma unroll
    for (int t = 0; t < 4; ++t) {
      const int d = dh * 128 + t * 32 + hi * 8;
      float wv[8], pwv[8];
      if (valid) {
        const float* lp = ld + (size_t)c * D_N + d;
        const float* pp = p  + (size_t)c * D_N + d;
        float4 l0 = *reinterpret_cast<const float4*>(lp);
        float4 l1 = *reinterpret_cast<const float4*>(lp + 4);
        float4 p0 = *reinterpret_cast<const float4*>(pp);
        float4 p1 = *reinterpret_cast<const float4*>(pp + 4);
        float lv[8] = {l0.x,l0.y,l0.z,l0.w,l1.x,l1.y,l1.z,l1.w};
        float pv[8] = {p0.x,p0.y,p0.z,p0.w,p1.x,p1.y,p1.z,p1.w};
#pragma unroll
        for (int j = 0; j < 8; ++j) {
          float wj = __expf(lv[j]);
          wv[j]  = wj;
          pwv[j] = -2.f * pv[j] * wj;
          sp += pv[j] * pv[j] * wj;
        }
      } else {
#pragma unroll
        for (int j = 0; j < 8; ++j) { wv[j] = 0.f; pwv[j] = 0.f; }
      }
      *reinterpret_cast<bf16x8*>(&lB[ct][dh * 4 + t][l][0])     = pack8(wv);
      *reinterpret_cast<bf16x8*>(&lB[ct][8 + dh * 4 + t][l][0]) = pack8(pwv);
    }
    sp += __shfl_xor(sp, 16, 64);
    sp += __shfl_xor(sp, 32, 64);
    if (l < 16) s_lds[dh][ct * 16 + r16] = sp;
  }

  // ---------------- prep: A' phase-0 (x^2), save raw x in regs ----------------
  {
    const int row = bx * 128 + w * 16 + r16;   // wave owns row-tile w
#pragma unroll
    for (int t = 0; t < 8; ++t) {
      const int d = t * 32 + hi * 8;
      const float* xp = x + (size_t)row * D_N + d;
      float4 v0 = *reinterpret_cast<const float4*>(xp);
      float4 v1 = *reinterpret_cast<const float4*>(xp + 4);
      float v[8] = {v0.x,v0.y,v0.z,v0.w,v1.x,v1.y,v1.z,v1.w};
      float sq[8];
#pragma unroll
      for (int j = 0; j < 8; ++j) sq[j] = v[j] * v[j];
      *reinterpret_cast<bf16x8*>(&lA[w][t][l][0]) = pack8(sq);
      xa_sv[t] = pack8(v);
    }
  }
  __syncthreads();

  // ---------------- compute: 8 waves 4x2, wave tile 32x32 ----------------
  const int wm = w >> 1, wn = w & 1;
  f32x4 acc[2][2];
#pragma unroll
  for (int i = 0; i < 2; ++i)
#pragma unroll
    for (int jn = 0; jn < 2; ++jn) acc[i][jn] = {0.f, 0.f, 0.f, 0.f};

  // phase 0: x^2 against w  (B ktiles 0..7)
#pragma unroll
  for (int kt = 0; kt < 8; ++kt) {
    bf16x8 a0 = *reinterpret_cast<const bf16x8*>(&lA[wm * 2 + 0][kt][l][0]);
    bf16x8 a1 = *reinterpret_cast<const bf16x8*>(&lA[wm * 2 + 1][kt][l][0]);
    bf16x8 b0 = *reinterpret_cast<const bf16x8*>(&lB[wn * 2 + 0][kt][l][0]);
    bf16x8 b1 = *reinterpret_cast<const bf16x8*>(&lB[wn * 2 + 1][kt][l][0]);
    acc[0][0] = __builtin_amdgcn_mfma_f32_16x16x32_bf16(a0, b0, acc[0][0], 0, 0, 0);
    acc[0][1] = __builtin_amdgcn_mfma_f32_16x16x32_bf16(a0, b1, acc[0][1], 0, 0, 0);
    acc[1][0] = __builtin_amdgcn_mfma_f32_16x16x32_bf16(a1, b0, acc[1][0], 0, 0, 0);
    acc[1][1] = __builtin_amdgcn_mfma_f32_16x16x32_bf16(a1, b1, acc[1][1], 0, 0, 0);
  }
  __syncthreads();                       // all reads of lA phase-0 done

  // A' phase-1: raw x, pure reg -> LDS
#pragma unroll
  for (int t = 0; t < 8; ++t)
    *reinterpret_cast<bf16x8*>(&lA[w][t][l][0]) = xa_sv[t];
  __syncthreads();

  // phase 1: x against -2*p*w  (B ktiles 8..15)
#pragma unroll
  for (int kt = 0; kt < 8; ++kt) {
    bf16x8 a0 = *reinterpret_cast<const bf16x8*>(&lA[wm * 2 + 0][kt][l][0]);
    bf16x8 a1 = *reinterpret_cast<const bf16x8*>(&lA[wm * 2 + 1][kt][l][0]);
    bf16x8 b0 = *reinterpret_cast<const bf16x8*>(&lB[wn * 2 + 0][8 + kt][l][0]);
    bf16x8 b1 = *reinterpret_cast<const bf16x8*>(&lB[wn * 2 + 1][8 + kt][l][0]);
    acc[0][0] = __builtin_amdgcn_mfma_f32_16x16x32_bf16(a0, b0, acc[0][0], 0, 0, 0);
    acc[0][1] = __builtin_amdgcn_mfma_f32_16x16x32_bf16(a0, b1, acc[0][1], 0, 0, 0);
    acc[1][0] = __builtin_amdgcn_mfma_f32_16x16x32_bf16(a1, b0, acc[1][0], 0, 0, 0);
    acc[1][1] = __builtin_amdgcn_mfma_f32_16x16x32_bf16(a1, b1, acc[1][1], 0, 0, 0);
  }

  // ---------------- epilogue ----------------
  // C/D layout: col = lane&15, row = (lane>>4)*4 + reg   [verified R1-R3]
  const int colbase = by * 64 + wn * 32 + r16;
  const int rowbase = bx * 128 + wm * 32 + hi * 4;
#pragma unroll
  for (int jn = 0; jn < 2; ++jn) {
    const int col = colbase + jn * 16;
    if (col < C_N) {
      const int ci = wn * 32 + jn * 16 + r16;
      const float sc = s_lds[0][ci] + s_lds[1][ci];
#pragma unroll
      for (int i = 0; i < 2; ++i) {
        const int row = rowbase + i * 16;
#pragma unroll
        for (int r = 0; r < 4; ++r)
          out[(size_t)(row + r) * C_N + col] = -(acc[i][jn][r] + sc);
      }
    }
  }
}

extern "C" void kernel_launch(void* const* d_in, const int* in_sizes, int n_in,
                              void* d_out, int out_size, void* d_ws, size_t ws_size,
                              hipStream_t stream) {
  const float* x  = (const float*)d_in[0];
  const float* p  = (const float*)d_in[1];
  const float* ld = (const float*)d_in[2];
  float* out = (float*)d_out;
  mahal_fused<<<dim3(16, 16), 512, 0, stream>>>(x, p, ld, out);
}

// Round 5
// 16.075 us; speedup vs baseline: 1.2490x; 1.0603x over previous
//
#include <hip/hip_runtime.h>
#include <hip/hip_bf16.h>

// MahalanobisClassifier, fused single dispatch, A-fragments register-resident.
// out[b,c] = -( sum_d x^2*w - 2 sum_d x*(p*w) + s[c] ),  w = exp(ld)
// bf16 MFMA GEMM, K=512 concat: A'=[x^2 | x], B'=[w | -2*p*w], s in epilogue.
//
// Block: 512 threads (8 waves), tile 128 rows x 64 classes, grid (16,16).
// Wave w owns output rows w*16..+15 (full 64 cols): its A' fragments are packed
// directly into VGPRs during prep (prep lane layout == MFMA A-frag layout:
// lane l -> row l&15, k (l>>4)*8+j — verified R1-R4). Only B' (64 KB) goes
// through LDS; ONE barrier; phase 0 (x^2 vs w) and phase 1 (x vs -2pw)
// interleave into dual accumulator chains with no intermediate sync.

#define C_N 1000
#define D_N 256

typedef __attribute__((ext_vector_type(8))) short bf16x8;
typedef __attribute__((ext_vector_type(4))) float f32x4;

__device__ inline bf16x8 pack8(const float* v) {
  union { bf16x8 o; __hip_bfloat162 h[4]; } u;
#pragma unroll
  for (int j = 0; j < 4; ++j)
    u.h[j] = __float22bfloat162_rn(make_float2(v[2 * j], v[2 * j + 1]));
  return u.o;
}

__global__ __launch_bounds__(512, 2) void mahal_fused(
    const float* __restrict__ x, const float* __restrict__ p,
    const float* __restrict__ ld, float* __restrict__ out) {
  __shared__ short lB[4][16][64][8];   // 64 KB: 4 class-tiles x 16 ktiles, frag order
  __shared__ float s_lds[2][64];

  const int tid = threadIdx.x;
  const int w   = tid >> 6;        // wave 0..7
  const int l   = tid & 63;
  const int r16 = l & 15;
  const int hi  = l >> 4;
  const int bx  = blockIdx.x;      // rows bx*128..+127
  const int by  = blockIdx.y;      // cols by*64..+63

  // ---------------- B' prep: waves split (class-tile, d-half) ----------------
  {
    const int ct = w & 3;          // class-tile 0..3
    const int dh = w >> 2;         // d-half 0..1
    const int c  = by * 64 + ct * 16 + r16;
    const bool valid = (c < C_N);
    float sp = 0.f;
#pragma unroll
    for (int t = 0; t < 4; ++t) {
      const int d = dh * 128 + t * 32 + hi * 8;
      float wv[8], pwv[8];
      if (valid) {
        const float* lp = ld + (size_t)c * D_N + d;
        const float* pp = p  + (size_t)c * D_N + d;
        float4 l0 = *reinterpret_cast<const float4*>(lp);
        float4 l1 = *reinterpret_cast<const float4*>(lp + 4);
        float4 p0 = *reinterpret_cast<const float4*>(pp);
        float4 p1 = *reinterpret_cast<const float4*>(pp + 4);
        float lv[8] = {l0.x,l0.y,l0.z,l0.w,l1.x,l1.y,l1.z,l1.w};
        float pv[8] = {p0.x,p0.y,p0.z,p0.w,p1.x,p1.y,p1.z,p1.w};
#pragma unroll
        for (int j = 0; j < 8; ++j) {
          float wj = __expf(lv[j]);
          wv[j]  = wj;
          pwv[j] = -2.f * pv[j] * wj;
          sp += pv[j] * pv[j] * wj;
        }
      } else {
#pragma unroll
        for (int j = 0; j < 8; ++j) { wv[j] = 0.f; pwv[j] = 0.f; }
      }
      *reinterpret_cast<bf16x8*>(&lB[ct][dh * 4 + t][l][0])     = pack8(wv);
      *reinterpret_cast<bf16x8*>(&lB[ct][8 + dh * 4 + t][l][0]) = pack8(pwv);
    }
    sp += __shfl_xor(sp, 16, 64);
    sp += __shfl_xor(sp, 32, 64);
    if (l < 16) s_lds[dh][ct * 16 + r16] = sp;
  }

  // ---------------- A' prep: straight into registers (frag order) ----------------
  bf16x8 aSq[8], aRaw[8];
  {
    const int row = bx * 128 + w * 16 + r16;   // wave w owns row-tile w
#pragma unroll
    for (int t = 0; t < 8; ++t) {
      const int d = t * 32 + hi * 8;
      const float* xp = x + (size_t)row * D_N + d;
      float4 v0 = *reinterpret_cast<const float4*>(xp);
      float4 v1 = *reinterpret_cast<const float4*>(xp + 4);
      float v[8] = {v0.x,v0.y,v0.z,v0.w,v1.x,v1.y,v1.z,v1.w};
      float sq[8];
#pragma unroll
      for (int j = 0; j < 8; ++j) sq[j] = v[j] * v[j];
      aSq[t]  = pack8(sq);
      aRaw[t] = pack8(v);
    }
  }
  __syncthreads();   // B' + s visible; the ONLY barrier

  // ---------------- compute: wave tile 16x64, dual phase-interleaved acc ----------------
  f32x4 acc0[4], acc1[4];
#pragma unroll
  for (int n = 0; n < 4; ++n) { acc0[n] = {0.f,0.f,0.f,0.f}; acc1[n] = {0.f,0.f,0.f,0.f}; }

#pragma unroll
  for (int kt = 0; kt < 8; ++kt) {
#pragma unroll
    for (int n = 0; n < 4; ++n) {
      bf16x8 b0 = *reinterpret_cast<const bf16x8*>(&lB[n][kt][l][0]);
      bf16x8 b1 = *reinterpret_cast<const bf16x8*>(&lB[n][8 + kt][l][0]);
      acc0[n] = __builtin_amdgcn_mfma_f32_16x16x32_bf16(aSq[kt],  b0, acc0[n], 0, 0, 0);
      acc1[n] = __builtin_amdgcn_mfma_f32_16x16x32_bf16(aRaw[kt], b1, acc1[n], 0, 0, 0);
    }
  }

  // ---------------- epilogue ----------------
  // C/D layout: col = lane&15, row = (lane>>4)*4 + reg   [verified R1-R4]
  const int rowbase = bx * 128 + w * 16 + hi * 4;
#pragma unroll
  for (int n = 0; n < 4; ++n) {
    const int col = by * 64 + n * 16 + r16;
    if (col < C_N) {
      const int ci = n * 16 + r16;
      const float sc = s_lds[0][ci] + s_lds[1][ci];
#pragma unroll
      for (int r = 0; r < 4; ++r)
        out[(size_t)(rowbase + r) * C_N + col] = -(acc0[n][r] + acc1[n][r] + sc);
    }
  }
}

extern "C" void kernel_launch(void* const* d_in, const int* in_sizes, int n_in,
                              void* d_out, int out_size, void* d_ws, size_t ws_size,
                              hipStream_t stream) {
  const float* x  = (const float*)d_in[0];
  const float* p  = (const float*)d_in[1];
  const float* ld = (const float*)d_in[2];
  float* out = (float*)d_out;
  mahal_fused<<<dim3(16, 16), 512, 0, stream>>>(x, p, ld, out);
}